// Round 3
// baseline (340.420 us; speedup 1.0000x reference)
//
#include <hip/hip_runtime.h>
#include <cstdint>
#include <cstddef>

typedef _Float16 f16x8 __attribute__((ext_vector_type(8)));
typedef _Float16 f16x4 __attribute__((ext_vector_type(4)));
typedef float f32x4 __attribute__((ext_vector_type(4)));

static __device__ __forceinline__ float elu_f(float t) {
    return t > 0.0f ? t : expm1f(t);
}

// XCD-aware block -> pooled-vertex-tile remap (XCD = bid & 7 round-robin).
static __device__ __forceinline__ int block_pu0(int bid, int P, int vshift_out, int nbl)
{
    if (nbl < 0) return bid * P;
    int xcd  = bid & 7;
    int slot = bid >> 3;
    int nb   = slot & ((1 << nbl) - 1);
    int tile = slot >> nbl;
    return ((xcd + (nb << 3)) << vshift_out) + tile * P;
}

// ---------------- weight prep: fp32 [K][C_OUT] -> fp16 tiled [y][t][kc][n][8] ----------------
template<int KTOT, int C_OUT, int BN>
__global__ __launch_bounds__(256)
void prep_w(const float* __restrict__ W, _Float16* __restrict__ o)
{
    constexpr int KT = KTOT/64;
    int i = blockIdx.x * 256 + threadIdx.x;
    if (i >= KTOT*C_OUT) return;
    int j = i & 7;
    int rest = i >> 3;
    int n = rest % BN;
    int kc = (rest / BN) & 7;
    int t = (rest / (BN*8)) % KT;
    int y = rest / (BN*8*KT);
    int k = t*64 + kc*8 + j;
    o[i] = (_Float16)W[(size_t)k*C_OUT + y*BN + n];
}

// Level-0 weights: (36,32) -> padded K=64, k = s*4 + c layout, tile [kc][n][8]
__global__ __launch_bounds__(256)
void prep_w0(const float* __restrict__ W, _Float16* __restrict__ o)
{
    int i = blockIdx.x * 256 + threadIdx.x;
    if (i >= 2048) return;
    int j = i & 7;
    int n = (i >> 3) & 31;
    int kc = i >> 8;
    int k = kc*8 + j;
    int s = k >> 2, c = k & 3;
    float v = (s < 12 && c < 3) ? W[(size_t)(s*3 + c)*32 + n] : 0.0f;
    o[i] = (_Float16)v;
}

// ---------------- x transpose: (16,32768,3) fp32 -> (32768,16,4) fp16 ----------------
__global__ __launch_bounds__(256)
void prep_xT(const float* __restrict__ x, _Float16* __restrict__ xT)
{
    __shared__ _Float16 t[16][64*4 + 8];
    const int v0 = blockIdx.x * 64;
    const int tid = threadIdx.x;
    #pragma unroll
    for (int it = 0; it < 4; ++it) {
        int e = it*256 + tid;          // 16 b x 64 v
        int b = e >> 6, v = e & 63;
        const float* p = x + ((size_t)b*32768 + v0 + v)*3;
        f16x4 h;
        h[0] = (_Float16)p[0]; h[1] = (_Float16)p[1];
        h[2] = (_Float16)p[2]; h[3] = (_Float16)0.f;
        *(f16x4*)&t[b][v*4] = h;
    }
    __syncthreads();
    #pragma unroll
    for (int it = 0; it < 2; ++it) {
        int e = it*256 + tid;          // 64 v x 8 s
        int vl = e >> 3, s = e & 7;
        f16x4 a = *(const f16x4*)&t[2*s][vl*4];
        f16x4 b = *(const f16x4*)&t[2*s+1][vl*4];
        f16x8 h;
        h[0]=a[0]; h[1]=a[1]; h[2]=a[2]; h[3]=a[3];
        h[4]=b[0]; h[5]=b[1]; h[6]=b[2]; h[7]=b[3];
        *(f16x8*)&xT[((size_t)(v0+vl)*16 + s*2)*4] = h;
    }
}

// ---------------- index pre-compose: didx0 o spiral0 -> u16-pair table ----------------
__global__ __launch_bounds__(256)
void prep_gidx(const int* __restrict__ didx, const int* __restrict__ spiral,
               unsigned int* __restrict__ g)
{
    int i = blockIdx.x*256 + threadIdx.x;   // 24576 rows x 8
    if (i >= 24576*8) return;
    int q = i & 7;
    int row = i >> 3;
    unsigned int val = 0;
    if (q < 6) {
        int v = didx[row];
        unsigned int s0 = (unsigned int)spiral[v*12 + q*2];
        unsigned int s1 = (unsigned int)spiral[v*12 + q*2 + 1];
        val = s0 | (s1 << 16);
    }
    g[i] = val;
}

// ---------------- conv0+pool0, batched-M over 16 batches ----------------
__global__ __launch_bounds__(256)
void conv0T(const _Float16* __restrict__ xT, const unsigned int* __restrict__ gidx,
            const _Float16* __restrict__ Wp, const float* __restrict__ bias,
            const float* __restrict__ dwt, _Float16* __restrict__ out)
{
    __shared__ _Float16 Ep[4][512];        // per-wave 1 KB transpose buffer
    const int tid  = threadIdx.x;
    const int wave = tid >> 6;
    const int lane = tid & 63;
    const int quad = lane >> 4;
    const int l16  = lane & 15;
    const int u0   = blockIdx.x * 8 + wave * 2;   // 2 u per wave

    f16x8 bf[2][2];
    #pragma unroll
    for (int kt = 0; kt < 2; ++kt)
        #pragma unroll
        for (int nt = 0; nt < 2; ++nt)
            bf[kt][nt] = *(const f16x8*)&Wp[(((kt*4+quad)*32) + nt*16 + l16)*8];
    float bv[2] = { bias[l16], bias[16 + l16] };

    #pragma unroll
    for (int ui = 0; ui < 2; ++ui) {
        int u = u0 + ui;
        f32x4 pacc[2] = {{0.f,0.f,0.f,0.f},{0.f,0.f,0.f,0.f}};
        #pragma unroll
        for (int kp = 0; kp < 3; ++kp) {
            int r = u*3 + kp;
            unsigned int gp0 = gidx[r*8 + quad];
            unsigned int gp1 = gidx[r*8 + 4 + quad];
            f16x4 a0 = *(const f16x4*)&xT[(size_t)(gp0 & 0xffffu)*64 + l16*4];
            f16x4 a1 = *(const f16x4*)&xT[(size_t)(gp0 >> 16)*64 + l16*4];
            f16x4 a2 = *(const f16x4*)&xT[(size_t)(gp1 & 0xffffu)*64 + l16*4];
            f16x4 a3 = *(const f16x4*)&xT[(size_t)(gp1 >> 16)*64 + l16*4];
            f16x8 af0, af1;
            af0[0]=a0[0]; af0[1]=a0[1]; af0[2]=a0[2]; af0[3]=a0[3];
            af0[4]=a1[0]; af0[5]=a1[1]; af0[6]=a1[2]; af0[7]=a1[3];
            af1[0]=a2[0]; af1[1]=a2[1]; af1[2]=a2[2]; af1[3]=a2[3];
            af1[4]=a3[0]; af1[5]=a3[1]; af1[6]=a3[2]; af1[7]=a3[3];
            float dw = dwt[r];
            #pragma unroll
            for (int nt = 0; nt < 2; ++nt) {
                f32x4 m = {0.f,0.f,0.f,0.f};
                m = __builtin_amdgcn_mfma_f32_16x16x32_f16(af0, bf[0][nt], m, 0,0,0);
                m = __builtin_amdgcn_mfma_f32_16x16x32_f16(af1, bf[1][nt], m, 0,0,0);
                #pragma unroll
                for (int rr = 0; rr < 4; ++rr)
                    pacc[nt][rr] += dw * elu_f(m[rr] + bv[nt]);
            }
        }
        #pragma unroll
        for (int nt = 0; nt < 2; ++nt)
            #pragma unroll
            for (int rr = 0; rr < 4; ++rr)
                Ep[wave][(quad*4+rr)*32 + nt*16 + l16] = (_Float16)pacc[nt][rr];
        int b  = lane >> 2;
        int c8 = lane & 3;
        f16x8 rowv = *(const f16x8*)&Ep[wave][b*32 + c8*8];
        *(f16x8*)&out[(size_t)b*262144 + (size_t)u*32 + c8*8] = rowv;
    }
}

// ---------------- fused conv+pool, direct-to-register MFMA + PINNED SW pipeline ----------------
// Rounds 0-2 post-mortem: at VGPR 48/32/52 the machine scheduler SANK every
// prefetch load next to its consuming MFMA (a held PIPE=4 pipeline needs ~80
// VGPR of fragments alone) -> each K-step serializes a full gather latency
// (2300 cyc/step vs ~90 cyc of issue work; MfmaUtil 7%, VALUBusy 8%).
// Source-level rotation is advisory; hipcc undoes it. This round PINS the
// cluster order with __builtin_amdgcn_sched_barrier(0): nothing may cross, so
// loads stay ~3.5 K-steps ahead of their MFMAs and the backend emits COUNTED
// vmcnt waits (~15 loads in flight/wave). Verification signal: VGPR must rise
// to ~130-170. K-step order and MFMA chaining unchanged -> identical numerics.
#define SBAR() __builtin_amdgcn_sched_barrier(0)

template<int C_IN, int C_OUT, int P, int BN, int WGM, int WGN, bool OUT_HALF, int PIPE>
__global__ __launch_bounds__(256)
void conv_pool_mfma(const _Float16* __restrict__ x, const int* __restrict__ spiral,
                    const _Float16* __restrict__ Wp, const float* __restrict__ bias,
                    const int* __restrict__ didx, const float* __restrict__ dwt,
                    void* __restrict__ outv, int vshift_in, int vshift_out, int nbl)
{
    constexpr int R    = 3*P;
    constexpr int KTOT = 12*C_IN;
    constexpr int KT   = KTOT/64;
    constexpr int NST  = KT*2;           // number of K=32 steps
    constexpr int WTM  = R/WGM;
    constexpr int WTN  = BN/WGN;
    constexpr int NMT  = WTM/16;
    constexpr int NNT  = WTN/16;
    constexpr int C4   = BN/4;
    static_assert(WTM % 16 == 0 && WTN % 16 == 0, "tile");
    static_assert(R <= 256 && (P*C4) % 256 == 0, "loops");
    static_assert(PIPE == 2 || PIPE == 4, "pipe");
    static_assert(PIPE != 2 || NST % 2 == 0, "pipe2");
    static_assert(PIPE != 4 || NST % 4 == 0, "pipe4");

    __shared__ unsigned short gidx[R*12];
    __shared__ _Float16 E[R*(BN+4)];

    const int tid  = threadIdx.x;
    const int wave = tid >> 6;
    const int lane = tid & 63;
    const int quad = lane >> 4;
    const int l16  = lane & 15;
    const int wm   = wave / WGN;
    const int wn   = wave % WGN;
    const int pu0  = block_pu0(blockIdx.x, P, vshift_out, nbl);
    const int n0   = blockIdx.y * BN;
    const int vmask_out = (1 << vshift_out) - 1;
    const int base_in = (pu0 >> vshift_out) << vshift_in;

    if (tid < R) {
        int ul = tid / 3;
        int kp = tid - ul*3;
        int u  = (pu0 + ul) & vmask_out;
        int v  = didx[u*3 + kp];
        const int* svp = spiral + v*12;
        #pragma unroll
        for (int j = 0; j < 12; ++j) gidx[tid*12 + j] = (unsigned short)svp[j];
    }
    __syncthreads();

    f32x4 acc[NMT][NNT];
    #pragma unroll
    for (int i = 0; i < NMT; ++i)
        #pragma unroll
        for (int j = 0; j < NNT; ++j) acc[i][j] = (f32x4){0.f, 0.f, 0.f, 0.f};

    const _Float16* xb = x + (size_t)base_in * C_IN;

    auto loadStep = [&](int s, f16x8* af, f16x8* bf) {
        const int k0 = s*32;
        const int sv = k0 / C_IN;
        const int c  = (k0 & (C_IN-1)) + quad*8;
        #pragma unroll
        for (int i = 0; i < NMT; ++i) {
            int m_local = wm*WTM + i*16 + l16;
            int g = gidx[m_local*12 + sv];
            af[i] = *(const f16x8*)&xb[(size_t)g*C_IN + c];
        }
        const _Float16* wsrc = Wp + ((size_t)(blockIdx.y*NST + s)*4 + quad)*BN*8;
        #pragma unroll
        for (int j = 0; j < NNT; ++j) {
            int n_local = wn*WTN + j*16 + l16;
            bf[j] = *(const f16x8*)&wsrc[n_local*8];
        }
    };
    auto mfmaStep = [&](const f16x8* af, const f16x8* bf) {
        #pragma unroll
        for (int i = 0; i < NMT; ++i)
            #pragma unroll
            for (int j = 0; j < NNT; ++j)
                acc[i][j] = __builtin_amdgcn_mfma_f32_16x16x32_f16(
                    af[i], bf[j], acc[i][j], 0, 0, 0);
    };

    if constexpr (PIPE == 2) {
        f16x8 afA[NMT], bfA[NNT], afB[NMT], bfB[NNT];
        loadStep(0, afA, bfA);
        SBAR();
        for (int st = 0; st < NST; st += 2) {
            loadStep(st + 1, afB, bfB);
            SBAR();
            mfmaStep(afA, bfA);
            SBAR();
            if (st + 2 < NST) loadStep(st + 2, afA, bfA);
            SBAR();
            mfmaStep(afB, bfB);
            SBAR();
        }
    } else {
        // 4-stage rotation, cluster order PINNED: each fragment set's loads are
        // issued 3-4 K-steps before their MFMAs and cannot be sunk.
        f16x8 afA[NMT], bfA[NNT], afB[NMT], bfB[NNT];
        f16x8 afC[NMT], bfC[NNT], afD[NMT], bfD[NNT];
        loadStep(0, afA, bfA);
        SBAR();
        loadStep(1, afB, bfB);
        SBAR();
        loadStep(2, afC, bfC);
        SBAR();
        for (int st = 0; st < NST; st += 4) {
            loadStep(st + 3, afD, bfD);                     // st+3 <= NST-1 always
            SBAR();
            mfmaStep(afA, bfA);
            SBAR();
            if (st + 4 < NST) loadStep(st + 4, afA, bfA);
            SBAR();
            mfmaStep(afB, bfB);
            SBAR();
            if (st + 5 < NST) loadStep(st + 5, afB, bfB);
            SBAR();
            mfmaStep(afC, bfC);
            SBAR();
            if (st + 6 < NST) loadStep(st + 6, afC, bfC);
            SBAR();
            mfmaStep(afD, bfD);
            SBAR();
        }
    }

    float bv[NNT];
    #pragma unroll
    for (int j = 0; j < NNT; ++j)
        bv[j] = bias[n0 + wn*WTN + j*16 + l16];

    #pragma unroll
    for (int i = 0; i < NMT; ++i) {
        int row_base = wm*WTM + i*16 + quad*4;
        #pragma unroll
        for (int j = 0; j < NNT; ++j) {
            int col = wn*WTN + j*16 + l16;
            #pragma unroll
            for (int r = 0; r < 4; ++r)
                E[(size_t)(row_base + r)*(BN+4) + col] =
                    (_Float16)elu_f(acc[i][j][r] + bv[j]);
        }
    }
    __syncthreads();

    #pragma unroll
    for (int e = tid; e < P*C4; e += 256) {
        int ul = e / C4;
        int c4 = e - ul*C4;
        int pu = pu0 + ul;
        int u  = pu & vmask_out;
        const float* w = dwt + u*3;
        f16x4 a0 = *(const f16x4*)&E[(size_t)(ul*3 + 0)*(BN+4) + c4*4];
        f16x4 a1 = *(const f16x4*)&E[(size_t)(ul*3 + 1)*(BN+4) + c4*4];
        f16x4 a2 = *(const f16x4*)&E[(size_t)(ul*3 + 2)*(BN+4) + c4*4];
        float ox = w[0]*(float)a0[0] + w[1]*(float)a1[0] + w[2]*(float)a2[0];
        float oy = w[0]*(float)a0[1] + w[1]*(float)a1[1] + w[2]*(float)a2[1];
        float oz = w[0]*(float)a0[2] + w[1]*(float)a1[2] + w[2]*(float)a2[2];
        float ow = w[0]*(float)a0[3] + w[1]*(float)a1[3] + w[2]*(float)a2[3];
        if (OUT_HALF) {
            f16x4 h; h[0]=(_Float16)ox; h[1]=(_Float16)oy; h[2]=(_Float16)oz; h[3]=(_Float16)ow;
            *(f16x4*)&((_Float16*)outv)[(size_t)pu*C_OUT + n0 + c4*4] = h;
        } else {
            float4 o; o.x=ox; o.y=oy; o.z=oz; o.w=ow;
            *(float4*)&((float*)outv)[(size_t)pu*C_OUT + n0 + c4*4] = o;
        }
    }
}

// ---------------- FC1: atomic-free split-K (ks=256, k-chunk 128) ----------------
__global__ __launch_bounds__(256)
void fc1_partial(const float* __restrict__ xflat, const float* __restrict__ Wl1,
                 float* __restrict__ partial)
{
    __shared__ float sb[8704];
    const int tid = threadIdx.x;
    const int n4 = tid & 31;
    const int kq = (tid >> 5) & 3;
    const int mh = tid >> 7;
    const int nt = blockIdx.x;
    const int ks = blockIdx.y;
    const int kbase = ks * 128;

    for (int e = tid; e < 1024; e += 256) {
        int m = e >> 5, k4 = e & 31;
        *(float4*)&sb[m*128 + k4*4] = *(const float4*)&xflat[(size_t)m*32768 + kbase + k4*4];
    }
    __syncthreads();

    float acc[16][4];
    #pragma unroll
    for (int m = 0; m < 16; ++m)
        #pragma unroll
        for (int c = 0; c < 4; ++c) acc[m][c] = 0.0f;

    const float* Wb = Wl1 + (size_t)(kbase + kq*32)*512 + nt*128 + n4*4;
    #pragma unroll 2
    for (int i = 0; i < 32; i += 4) {
        float4 w0 = *(const float4*)(Wb + (size_t)(i+0)*512);
        float4 w1 = *(const float4*)(Wb + (size_t)(i+1)*512);
        float4 w2 = *(const float4*)(Wb + (size_t)(i+2)*512);
        float4 w3 = *(const float4*)(Wb + (size_t)(i+3)*512);
        #pragma unroll
        for (int m = 0; m < 16; ++m) {
            float4 xv = *(const float4*)&sb[(mh*16 + m)*128 + kq*32 + i];
            acc[m][0] += xv.x*w0.x + xv.y*w1.x + xv.z*w2.x + xv.w*w3.x;
            acc[m][1] += xv.x*w0.y + xv.y*w1.y + xv.z*w2.y + xv.w*w3.y;
            acc[m][2] += xv.x*w0.z + xv.y*w1.z + xv.z*w2.z + xv.w*w3.z;
            acc[m][3] += xv.x*w0.w + xv.y*w1.w + xv.z*w2.w + xv.w*w3.w;
        }
    }
    __syncthreads();

    int slot = (mh*2 + (kq >> 1))*32 + n4;
    if (kq & 1) {
        #pragma unroll
        for (int m = 0; m < 16; ++m)
            *(float4*)&sb[slot*68 + m*4] = *(float4*)&acc[m][0];
    }
    __syncthreads();
    if (!(kq & 1)) {
        #pragma unroll
        for (int m = 0; m < 16; ++m) {
            float4 v = *(const float4*)&sb[slot*68 + m*4];
            acc[m][0] += v.x; acc[m][1] += v.y; acc[m][2] += v.z; acc[m][3] += v.w;
        }
    }
    __syncthreads();
    int slot2 = mh*32 + n4;
    if (kq == 2) {
        #pragma unroll
        for (int m = 0; m < 16; ++m)
            *(float4*)&sb[slot2*68 + m*4] = *(float4*)&acc[m][0];
    }
    __syncthreads();
    if (kq == 0) {
        float* pb = partial + ((size_t)(ks*4 + nt)*32 + mh*16)*128 + n4*4;
        #pragma unroll
        for (int m = 0; m < 16; ++m) {
            float4 v = *(const float4*)&sb[slot2*68 + m*4];
            float4 o;
            o.x = acc[m][0] + v.x; o.y = acc[m][1] + v.y;
            o.z = acc[m][2] + v.z; o.w = acc[m][3] + v.w;
            *(float4*)(pb + (size_t)m*128) = o;
        }
    }
}

__global__ __launch_bounds__(256)
void fc1_reduce(const float* __restrict__ partial, const float* __restrict__ bl1,
                float* __restrict__ hout)
{
    int i = blockIdx.x * 256 + threadIdx.x;
    int m = i >> 9, n = i & 511;
    int nt = n >> 7, nl = n & 127;
    const float* p = partial + ((size_t)nt*32 + m)*128 + nl;
    float s = 0.0f;
    #pragma unroll 8
    for (int ks = 0; ks < 256; ++ks)
        s += p[(size_t)ks*4*4096];
    hout[i] = elu_f(s + bl1[n]);
}

__global__ __launch_bounds__(64)
void fc2_kernel(const float* __restrict__ h, const float* __restrict__ Wl2,
                const float* __restrict__ bl2, float* __restrict__ y)
{
    int m = blockIdx.x;
    int n = threadIdx.x;
    float s = bl2[n];
    for (int k = 0; k < 512; ++k)
        s += h[(size_t)m*512 + k] * Wl2[(size_t)k*64 + n];
    y[(size_t)m*64 + n] = s;
}

extern "C" void kernel_launch(void* const* d_in, const int* in_sizes, int n_in,
                              void* d_out, int out_size, void* d_ws, size_t ws_size,
                              hipStream_t stream)
{
    (void)in_sizes; (void)n_in; (void)out_size; (void)ws_size;

    const float* x0 = (const float*)d_in[0];
    const int*   sp[4]; const int* didx[4]; const float* dwp[4];
    const float* Wp[4]; const float* bp[4];
    for (int i = 0; i < 4; ++i) {
        sp[i]   = (const int*)  d_in[1 + i*5 + 0];
        didx[i] = (const int*)  d_in[1 + i*5 + 1];
        dwp[i]  = (const float*)d_in[1 + i*5 + 2];
        Wp[i]   = (const float*)d_in[1 + i*5 + 3];
        bp[i]   = (const float*)d_in[1 + i*5 + 4];
    }
    const float* Wl1 = (const float*)d_in[21];
    const float* bl1 = (const float*)d_in[22];
    const float* Wl2 = (const float*)d_in[23];
    const float* bl2 = (const float*)d_in[24];
    float* out = (float*)d_out;

    char* wsb = (char*)d_ws;
    float* persist      = (float*)wsb;                    // 4 MB   (32,128,256) fp32
    float* partial      = (float*)(wsb + (4<<20));        // 16.8 MB (1024 x 4096 f32)
    _Float16* xT        = (_Float16*)(wsb + (24<<20));    // 8 MB   (2 halves x 4 MB)
    _Float16* pooled0   = (_Float16*)(wsb + (32<<20));    // 16 MB  (32,8192,32) fp16
    _Float16* pooled1   = (_Float16*)(wsb + (48<<20));    // 8 MB   (32,2048,64) fp16
    _Float16* pooled2   = (_Float16*)(wsb + (56<<20));    // 4 MB   (32,512,128) fp16
    unsigned int* gidx0 = (unsigned int*)(wsb + (60<<20));// 0.75 MB
    _Float16* w0h       = (_Float16*)(wsb + (61<<20));
    _Float16* w1h       = w0h + 2048;
    _Float16* w2h       = w1h + 24576;
    _Float16* w3h       = w2h + 98304;

    prep_w0<<<8, 256, 0, stream>>>(Wp[0], w0h);
    prep_w< 384,  64,  64><<<( 24576 + 255)/256, 256, 0, stream>>>(Wp[1], w1h);
    prep_w< 768, 128, 128><<<( 98304 + 255)/256, 256, 0, stream>>>(Wp[2], w2h);
    prep_w<1536, 256,  64><<<(393216 + 255)/256, 256, 0, stream>>>(Wp[3], w3h);
    prep_gidx<<<768, 256, 0, stream>>>(didx[0], sp[0], gidx0);

    // L0: x transpose + batched-M conv0 (2 dispatches of 16 batches each)
    for (int h = 0; h < 2; ++h) {
        _Float16* xTh = xT + (size_t)h*2097152;
        prep_xT<<<512, 256, 0, stream>>>(x0 + (size_t)h*16*98304, xTh);
        conv0T<<<1024, 256, 0, stream>>>(xTh, gidx0, w0h, bp[0], dwp[0],
                                         pooled0 + (size_t)h*16*262144);
    }

    // L1: conv(32->64, K=384) + pool -> fp16 (32, 2048, 64)
    //     round-0 geometry, PIPE=4 with sched_barrier-pinned clusters
    conv_pool_mfma<32,64,64,64,4,1,true,4><<<1024, 256, 0, stream>>>(
        pooled0, sp[1], w1h, bp[1], didx[1], dwp[1], pooled1, 13, 11, 2);

    // L2: conv(64->128, K=768) + pool -> fp16 (32, 512, 128)
    conv_pool_mfma<64,128,32,128,2,2,true,4><<<512, 256, 0, stream>>>(
        pooled1, sp[2], w2h, bp[2], didx[2], dwp[2], pooled2, 11, 9, 2);

    // L3: conv(128->256, K=1536) + pool -> fp32 persist (32, 128, 256)
    conv_pool_mfma<128,256,32,64,2,2,false,4><<<dim3(128, 4), 256, 0, stream>>>(
        pooled2, sp[3], w3h, bp[3], didx[3], dwp[3], persist, 9, 7, 2);

    // FC1: (32,32768)@(32768,512), split-K partials then reduce+bias+ELU
    fc1_partial<<<dim3(4, 256), 256, 0, stream>>>(persist, Wl1, partial);
    fc1_reduce<<<64, 256, 0, stream>>>(partial, bl1, out);

    // FC2: (32,512)@(512,64) + bias -> d_out[16384:18432]
    fc2_kernel<<<32, 64, 0, stream>>>(out, Wl2, bl2, out + 16384);
}

// Round 4
// 292.916 us; speedup vs baseline: 1.1622x; 1.1622x over previous
//
#include <hip/hip_runtime.h>
#include <cstdint>
#include <cstddef>

typedef _Float16 f16x8 __attribute__((ext_vector_type(8)));
typedef _Float16 f16x4 __attribute__((ext_vector_type(4)));
typedef float f32x4 __attribute__((ext_vector_type(4)));

static __device__ __forceinline__ float elu_f(float t) {
    return t > 0.0f ? t : expm1f(t);
}

// async global->LDS 16B copy: per-lane GLOBAL source, linear LDS dest
// (wave-uniform base + lane*16).
typedef __attribute__((address_space(1))) const unsigned int guint;
typedef __attribute__((address_space(3))) unsigned int       luint;
static __device__ __forceinline__ void gload_lds16(const void* g, void* l)
{
    __builtin_amdgcn_global_load_lds((guint*)g, (luint*)l, 16, 0, 0);
}

// XCD-aware block -> pooled-vertex-tile remap (XCD = bid & 7 round-robin).
static __device__ __forceinline__ int block_pu0(int bid, int P, int vshift_out, int nbl)
{
    if (nbl < 0) return bid * P;
    int xcd  = bid & 7;
    int slot = bid >> 3;
    int nb   = slot & ((1 << nbl) - 1);
    int tile = slot >> nbl;
    return ((xcd + (nb << 3)) << vshift_out) + tile * P;
}

// ---------------- weight prep: fp32 [K][C_OUT] -> fp16 tiled [y][t][kc][n][8] ----------------
template<int KTOT, int C_OUT, int BN>
__global__ __launch_bounds__(256)
void prep_w(const float* __restrict__ W, _Float16* __restrict__ o)
{
    constexpr int KT = KTOT/64;
    int i = blockIdx.x * 256 + threadIdx.x;
    if (i >= KTOT*C_OUT) return;
    int j = i & 7;
    int rest = i >> 3;
    int n = rest % BN;
    int kc = (rest / BN) & 7;
    int t = (rest / (BN*8)) % KT;
    int y = rest / (BN*8*KT);
    int k = t*64 + kc*8 + j;
    o[i] = (_Float16)W[(size_t)k*C_OUT + y*BN + n];
}

// Level-0 weights: (36,32) -> padded K=64, k = s*4 + c layout, tile [kc][n][8]
__global__ __launch_bounds__(256)
void prep_w0(const float* __restrict__ W, _Float16* __restrict__ o)
{
    int i = blockIdx.x * 256 + threadIdx.x;
    if (i >= 2048) return;
    int j = i & 7;
    int n = (i >> 3) & 31;
    int kc = i >> 8;
    int k = kc*8 + j;
    int s = k >> 2, c = k & 3;
    float v = (s < 12 && c < 3) ? W[(size_t)(s*3 + c)*32 + n] : 0.0f;
    o[i] = (_Float16)v;
}

// ---------------- x transpose: (16,32768,3) fp32 -> (32768,16,4) fp16 ----------------
__global__ __launch_bounds__(256)
void prep_xT(const float* __restrict__ x, _Float16* __restrict__ xT)
{
    __shared__ _Float16 t[16][64*4 + 8];
    const int v0 = blockIdx.x * 64;
    const int tid = threadIdx.x;
    #pragma unroll
    for (int it = 0; it < 4; ++it) {
        int e = it*256 + tid;          // 16 b x 64 v
        int b = e >> 6, v = e & 63;
        const float* p = x + ((size_t)b*32768 + v0 + v)*3;
        f16x4 h;
        h[0] = (_Float16)p[0]; h[1] = (_Float16)p[1];
        h[2] = (_Float16)p[2]; h[3] = (_Float16)0.f;
        *(f16x4*)&t[b][v*4] = h;
    }
    __syncthreads();
    #pragma unroll
    for (int it = 0; it < 2; ++it) {
        int e = it*256 + tid;          // 64 v x 8 s
        int vl = e >> 3, s = e & 7;
        f16x4 a = *(const f16x4*)&t[2*s][vl*4];
        f16x4 b = *(const f16x4*)&t[2*s+1][vl*4];
        f16x8 h;
        h[0]=a[0]; h[1]=a[1]; h[2]=a[2]; h[3]=a[3];
        h[4]=b[0]; h[5]=b[1]; h[6]=b[2]; h[7]=b[3];
        *(f16x8*)&xT[((size_t)(v0+vl)*16 + s*2)*4] = h;
    }
}

// ---------------- index pre-compose: didx0 o spiral0 -> u16-pair table ----------------
__global__ __launch_bounds__(256)
void prep_gidx(const int* __restrict__ didx, const int* __restrict__ spiral,
               unsigned int* __restrict__ g)
{
    int i = blockIdx.x*256 + threadIdx.x;   // 24576 rows x 8
    if (i >= 24576*8) return;
    int q = i & 7;
    int row = i >> 3;
    unsigned int val = 0;
    if (q < 6) {
        int v = didx[row];
        unsigned int s0 = (unsigned int)spiral[v*12 + q*2];
        unsigned int s1 = (unsigned int)spiral[v*12 + q*2 + 1];
        val = s0 | (s1 << 16);
    }
    g[i] = val;
}

// ---------------- conv0+pool0, batched-M over 16 batches ----------------
__global__ __launch_bounds__(256)
void conv0T(const _Float16* __restrict__ xT, const unsigned int* __restrict__ gidx,
            const _Float16* __restrict__ Wp, const float* __restrict__ bias,
            const float* __restrict__ dwt, _Float16* __restrict__ out)
{
    __shared__ _Float16 Ep[4][512];        // per-wave 1 KB transpose buffer
    const int tid  = threadIdx.x;
    const int wave = tid >> 6;
    const int lane = tid & 63;
    const int quad = lane >> 4;
    const int l16  = lane & 15;
    const int u0   = blockIdx.x * 8 + wave * 2;   // 2 u per wave

    f16x8 bf[2][2];
    #pragma unroll
    for (int kt = 0; kt < 2; ++kt)
        #pragma unroll
        for (int nt = 0; nt < 2; ++nt)
            bf[kt][nt] = *(const f16x8*)&Wp[(((kt*4+quad)*32) + nt*16 + l16)*8];
    float bv[2] = { bias[l16], bias[16 + l16] };

    #pragma unroll
    for (int ui = 0; ui < 2; ++ui) {
        int u = u0 + ui;
        f32x4 pacc[2] = {{0.f,0.f,0.f,0.f},{0.f,0.f,0.f,0.f}};
        #pragma unroll
        for (int kp = 0; kp < 3; ++kp) {
            int r = u*3 + kp;
            unsigned int gp0 = gidx[r*8 + quad];
            unsigned int gp1 = gidx[r*8 + 4 + quad];
            f16x4 a0 = *(const f16x4*)&xT[(size_t)(gp0 & 0xffffu)*64 + l16*4];
            f16x4 a1 = *(const f16x4*)&xT[(size_t)(gp0 >> 16)*64 + l16*4];
            f16x4 a2 = *(const f16x4*)&xT[(size_t)(gp1 & 0xffffu)*64 + l16*4];
            f16x4 a3 = *(const f16x4*)&xT[(size_t)(gp1 >> 16)*64 + l16*4];
            f16x8 af0, af1;
            af0[0]=a0[0]; af0[1]=a0[1]; af0[2]=a0[2]; af0[3]=a0[3];
            af0[4]=a1[0]; af0[5]=a1[1]; af0[6]=a1[2]; af0[7]=a1[3];
            af1[0]=a2[0]; af1[1]=a2[1]; af1[2]=a2[2]; af1[3]=a2[3];
            af1[4]=a3[0]; af1[5]=a3[1]; af1[6]=a3[2]; af1[7]=a3[3];
            float dw = dwt[r];
            #pragma unroll
            for (int nt = 0; nt < 2; ++nt) {
                f32x4 m = {0.f,0.f,0.f,0.f};
                m = __builtin_amdgcn_mfma_f32_16x16x32_f16(af0, bf[0][nt], m, 0,0,0);
                m = __builtin_amdgcn_mfma_f32_16x16x32_f16(af1, bf[1][nt], m, 0,0,0);
                #pragma unroll
                for (int rr = 0; rr < 4; ++rr)
                    pacc[nt][rr] += dw * elu_f(m[rr] + bv[nt]);
            }
        }
        #pragma unroll
        for (int nt = 0; nt < 2; ++nt)
            #pragma unroll
            for (int rr = 0; rr < 4; ++rr)
                Ep[wave][(quad*4+rr)*32 + nt*16 + l16] = (_Float16)pacc[nt][rr];
        int b  = lane >> 2;
        int c8 = lane & 3;
        f16x8 rowv = *(const f16x8*)&Ep[wave][b*32 + c8*8];
        *(f16x8*)&out[(size_t)b*262144 + (size_t)u*32 + c8*8] = rowv;
    }
}

// ---------------- fused conv+pool: async LDS staging (m97 structure) ----------------
// Rounds 0-3 post-mortem: register-resident prefetch of the scattered A-gather
// is unwinnable at HIP source level -- the backend either sinks the loads
// (R1/R2) or drains vmcnt(0) per MFMA cluster (R3, sched_barrier'd). All three
// measured neutral-or-worse with MfmaUtil ~7%.
// This round: canonical global_load_lds double-buffered staging. Per group of
// GS K-steps: stage(g+1) async into LDS buffer ^1 (gathered per-lane global
// source, LINEAR LDS dest), compute group g from LDS via ds_read_b128, one
// __syncthreads(). The staged loads have the whole compute phase to land, and
// staging needs no registers -> nothing for the scheduler to sink.
// A-tile bank conflicts (row stride 64-256B) fixed by BOTH-sides chunk XOR
// swizzle: source chunk q^swz(r) staged at slot q, reader reads slot c^swz(r).
// E/pool buffer overlays the (dead-after-K-loop) staging buffers.
// MFMA order per K-step unchanged -> identical numerics.
template<int C_IN, int C_OUT, int P, int BN, int WGM, int WGN, bool OUT_HALF>
__global__ __launch_bounds__(256)
void conv_pool_mfma(const _Float16* __restrict__ x, const int* __restrict__ spiral,
                    const _Float16* __restrict__ Wp, const float* __restrict__ bias,
                    const int* __restrict__ didx, const float* __restrict__ dwt,
                    void* __restrict__ outv, int vshift_in, int vshift_out, int nbl)
{
    constexpr int R    = 3*P;
    constexpr int KTOT = 12*C_IN;
    constexpr int KT   = KTOT/64;
    constexpr int NST  = KT*2;           // number of K=32 steps
    constexpr int WTM  = R/WGM;
    constexpr int WTN  = BN/WGN;
    constexpr int NMT  = WTM/16;
    constexpr int NNT  = WTN/16;
    constexpr int C4   = BN/4;
    constexpr int GS   = (C_IN == 32) ? 1 : 2;   // K-steps per staging group
    constexpr int NG   = NST / GS;
    constexpr int CPR  = GS * 4;         // 16B chunks per staged row-part (4 or 8)
    constexpr int CPRS = (CPR == 4) ? 2 : 3;
    constexpr int ACH  = R * CPR;        // A chunks per group
    constexpr int BCH  = GS * BN * 4;    // B chunks per group
    constexpr int AIPW = ACH / 256;      // global_load_lds instrs per wave
    constexpr int BIPW = BCH / 256;
    constexpr int ASUBH = R * GS * 32;   // halfs per A sub-buffer
    constexpr int BSUBH = GS * 32 * BN;  // halfs per B sub-buffer
    static_assert(WTM % 16 == 0 && WTN % 16 == 0, "tile");
    static_assert(R <= 256 && (P*C4) % 256 == 0, "loops");
    static_assert(ACH % 256 == 0 && BCH % 256 == 0, "stage");
    static_assert(NST % GS == 0 && GS*32 <= C_IN, "group");

    constexpr size_t BUFB = (size_t)(2*ASUBH + 2*BSUBH) * 2;
    constexpr size_t EB   = (size_t)R * (BN + 4) * 2;
    constexpr size_t GOFF = (BUFB > EB ? BUFB : EB);
    __shared__ __align__(16) char smem[GOFF + (size_t)R*12*2];
    _Float16* Ab = (_Float16*)smem;
    _Float16* Bb = (_Float16*)(smem + (size_t)2*ASUBH*2);
    unsigned short* gidx = (unsigned short*)(smem + GOFF);
    _Float16* E = (_Float16*)smem;       // overlays staging bufs (dead after K-loop)

    const int tid  = threadIdx.x;
    const int wave = tid >> 6;
    const int lane = tid & 63;
    const int quad = lane >> 4;
    const int l16  = lane & 15;
    const int wm   = wave / WGN;
    const int wn   = wave % WGN;
    const int pu0  = block_pu0(blockIdx.x, P, vshift_out, nbl);
    const int n0   = blockIdx.y * BN;
    const int vmask_out = (1 << vshift_out) - 1;
    const int base_in = (pu0 >> vshift_out) << vshift_in;

    if (tid < R) {
        int ul = tid / 3;
        int kp = tid - ul*3;
        int u  = (pu0 + ul) & vmask_out;
        int v  = didx[u*3 + kp];
        const int* svp = spiral + v*12;
        #pragma unroll
        for (int j = 0; j < 12; ++j) gidx[tid*12 + j] = (unsigned short)svp[j];
    }
    __syncthreads();

    f32x4 acc[NMT][NNT];
    #pragma unroll
    for (int i = 0; i < NMT; ++i)
        #pragma unroll
        for (int j = 0; j < NNT; ++j) acc[i][j] = (f32x4){0.f, 0.f, 0.f, 0.f};

    const _Float16* xb = x + (size_t)base_in * C_IN;

    // chunk swizzle: slot q of row r holds global chunk q ^ SWZ(r)
    auto SWZ = [](int r) -> int {
        return (CPR == 4) ? ((r & 3) ^ ((r >> 2) & 3)) : (r & 7);
    };

    auto stage = [&](int g, int buf) {
        const int k0g = g * GS * 32;
        const int sv  = k0g / C_IN;
        const int c0  = k0g % C_IN;                  // halfs
        _Float16* Ad = Ab + (size_t)buf * ASUBH;
        #pragma unroll
        for (int i = 0; i < AIPW; ++i) {
            int t  = (wave*AIPW + i)*64 + lane;
            int r  = t >> CPRS;
            int q  = t & (CPR - 1);
            int qq = q ^ SWZ(r);
            int gr = gidx[r*12 + sv];
            gload_lds16(xb + (size_t)gr*C_IN + c0 + qq*8,
                        Ad + (size_t)(wave*AIPW + i)*512);
        }
        _Float16* Bd = Bb + (size_t)buf * BSUBH;
        const _Float16* bs = Wp + ((size_t)(blockIdx.y*NST + g*GS)*4)*BN*8;
        #pragma unroll
        for (int i = 0; i < BIPW; ++i) {
            int t = (wave*BIPW + i)*64 + lane;
            gload_lds16(bs + (size_t)t*8,
                        Bd + (size_t)(wave*BIPW + i)*512);
        }
    };

    stage(0, 0);
    __syncthreads();

    for (int g = 0; g < NG; ++g) {
        const int cur = g & 1;
        if (g + 1 < NG) stage(g + 1, cur ^ 1);
        const _Float16* Ar = Ab + (size_t)cur * ASUBH;
        const _Float16* Br = Bb + (size_t)cur * BSUBH;
        #pragma unroll
        for (int sl = 0; sl < GS; ++sl) {
            f16x8 af[NMT], bf[NNT];
            #pragma unroll
            for (int i = 0; i < NMT; ++i) {
                int m = wm*WTM + i*16 + l16;
                af[i] = *(const f16x8*)&Ar[(size_t)(m*CPR + ((sl*4 + quad) ^ SWZ(m)))*8];
            }
            #pragma unroll
            for (int j = 0; j < NNT; ++j) {
                int n = wn*WTN + j*16 + l16;
                bf[j] = *(const f16x8*)&Br[(size_t)((sl*4 + quad)*BN + n)*8];
            }
            #pragma unroll
            for (int i = 0; i < NMT; ++i)
                #pragma unroll
                for (int j = 0; j < NNT; ++j)
                    acc[i][j] = __builtin_amdgcn_mfma_f32_16x16x32_f16(
                        af[i], bf[j], acc[i][j], 0, 0, 0);
        }
        __syncthreads();   // drains stage(g+1) loads; frees buf cur for stage(g+2)
    }

    float bv[NNT];
    #pragma unroll
    for (int j = 0; j < NNT; ++j)
        bv[j] = bias[n0 + wn*WTN + j*16 + l16];

    #pragma unroll
    for (int i = 0; i < NMT; ++i) {
        int row_base = wm*WTM + i*16 + quad*4;
        #pragma unroll
        for (int j = 0; j < NNT; ++j) {
            int col = wn*WTN + j*16 + l16;
            #pragma unroll
            for (int r = 0; r < 4; ++r)
                E[(size_t)(row_base + r)*(BN+4) + col] =
                    (_Float16)elu_f(acc[i][j][r] + bv[j]);
        }
    }
    __syncthreads();

    #pragma unroll
    for (int e = tid; e < P*C4; e += 256) {
        int ul = e / C4;
        int c4 = e - ul*C4;
        int pu = pu0 + ul;
        int u  = pu & vmask_out;
        const float* w = dwt + u*3;
        f16x4 a0 = *(const f16x4*)&E[(size_t)(ul*3 + 0)*(BN+4) + c4*4];
        f16x4 a1 = *(const f16x4*)&E[(size_t)(ul*3 + 1)*(BN+4) + c4*4];
        f16x4 a2 = *(const f16x4*)&E[(size_t)(ul*3 + 2)*(BN+4) + c4*4];
        float ox = w[0]*(float)a0[0] + w[1]*(float)a1[0] + w[2]*(float)a2[0];
        float oy = w[0]*(float)a0[1] + w[1]*(float)a1[1] + w[2]*(float)a2[1];
        float oz = w[0]*(float)a0[2] + w[1]*(float)a1[2] + w[2]*(float)a2[2];
        float ow = w[0]*(float)a0[3] + w[1]*(float)a1[3] + w[2]*(float)a2[3];
        if (OUT_HALF) {
            f16x4 h; h[0]=(_Float16)ox; h[1]=(_Float16)oy; h[2]=(_Float16)oz; h[3]=(_Float16)ow;
            *(f16x4*)&((_Float16*)outv)[(size_t)pu*C_OUT + n0 + c4*4] = h;
        } else {
            float4 o; o.x=ox; o.y=oy; o.z=oz; o.w=ow;
            *(float4*)&((float*)outv)[(size_t)pu*C_OUT + n0 + c4*4] = o;
        }
    }
}

// ---------------- FC1: atomic-free split-K (ks=256, k-chunk 128) ----------------
__global__ __launch_bounds__(256)
void fc1_partial(const float* __restrict__ xflat, const float* __restrict__ Wl1,
                 float* __restrict__ partial)
{
    __shared__ float sb[8704];
    const int tid = threadIdx.x;
    const int n4 = tid & 31;
    const int kq = (tid >> 5) & 3;
    const int mh = tid >> 7;
    const int nt = blockIdx.x;
    const int ks = blockIdx.y;
    const int kbase = ks * 128;

    for (int e = tid; e < 1024; e += 256) {
        int m = e >> 5, k4 = e & 31;
        *(float4*)&sb[m*128 + k4*4] = *(const float4*)&xflat[(size_t)m*32768 + kbase + k4*4];
    }
    __syncthreads();

    float acc[16][4];
    #pragma unroll
    for (int m = 0; m < 16; ++m)
        #pragma unroll
        for (int c = 0; c < 4; ++c) acc[m][c] = 0.0f;

    const float* Wb = Wl1 + (size_t)(kbase + kq*32)*512 + nt*128 + n4*4;
    #pragma unroll 2
    for (int i = 0; i < 32; i += 4) {
        float4 w0 = *(const float4*)(Wb + (size_t)(i+0)*512);
        float4 w1 = *(const float4*)(Wb + (size_t)(i+1)*512);
        float4 w2 = *(const float4*)(Wb + (size_t)(i+2)*512);
        float4 w3 = *(const float4*)(Wb + (size_t)(i+3)*512);
        #pragma unroll
        for (int m = 0; m < 16; ++m) {
            float4 xv = *(const float4*)&sb[(mh*16 + m)*128 + kq*32 + i];
            acc[m][0] += xv.x*w0.x + xv.y*w1.x + xv.z*w2.x + xv.w*w3.x;
            acc[m][1] += xv.x*w0.y + xv.y*w1.y + xv.z*w2.y + xv.w*w3.y;
            acc[m][2] += xv.x*w0.z + xv.y*w1.z + xv.z*w2.z + xv.w*w3.z;
            acc[m][3] += xv.x*w0.w + xv.y*w1.w + xv.z*w2.w + xv.w*w3.w;
        }
    }
    __syncthreads();

    int slot = (mh*2 + (kq >> 1))*32 + n4;
    if (kq & 1) {
        #pragma unroll
        for (int m = 0; m < 16; ++m)
            *(float4*)&sb[slot*68 + m*4] = *(float4*)&acc[m][0];
    }
    __syncthreads();
    if (!(kq & 1)) {
        #pragma unroll
        for (int m = 0; m < 16; ++m) {
            float4 v = *(const float4*)&sb[slot*68 + m*4];
            acc[m][0] += v.x; acc[m][1] += v.y; acc[m][2] += v.z; acc[m][3] += v.w;
        }
    }
    __syncthreads();
    int slot2 = mh*32 + n4;
    if (kq == 2) {
        #pragma unroll
        for (int m = 0; m < 16; ++m)
            *(float4*)&sb[slot2*68 + m*4] = *(float4*)&acc[m][0];
    }
    __syncthreads();
    if (kq == 0) {
        float* pb = partial + ((size_t)(ks*4 + nt)*32 + mh*16)*128 + n4*4;
        #pragma unroll
        for (int m = 0; m < 16; ++m) {
            float4 v = *(const float4*)&sb[slot2*68 + m*4];
            float4 o;
            o.x = acc[m][0] + v.x; o.y = acc[m][1] + v.y;
            o.z = acc[m][2] + v.z; o.w = acc[m][3] + v.w;
            *(float4*)(pb + (size_t)m*128) = o;
        }
    }
}

__global__ __launch_bounds__(256)
void fc1_reduce(const float* __restrict__ partial, const float* __restrict__ bl1,
                float* __restrict__ hout)
{
    int i = blockIdx.x * 256 + threadIdx.x;
    int m = i >> 9, n = i & 511;
    int nt = n >> 7, nl = n & 127;
    const float* p = partial + ((size_t)nt*32 + m)*128 + nl;
    float s = 0.0f;
    #pragma unroll 8
    for (int ks = 0; ks < 256; ++ks)
        s += p[(size_t)ks*4*4096];
    hout[i] = elu_f(s + bl1[n]);
}

__global__ __launch_bounds__(64)
void fc2_kernel(const float* __restrict__ h, const float* __restrict__ Wl2,
                const float* __restrict__ bl2, float* __restrict__ y)
{
    int m = blockIdx.x;
    int n = threadIdx.x;
    float s = bl2[n];
    for (int k = 0; k < 512; ++k)
        s += h[(size_t)m*512 + k] * Wl2[(size_t)k*64 + n];
    y[(size_t)m*64 + n] = s;
}

extern "C" void kernel_launch(void* const* d_in, const int* in_sizes, int n_in,
                              void* d_out, int out_size, void* d_ws, size_t ws_size,
                              hipStream_t stream)
{
    (void)in_sizes; (void)n_in; (void)out_size; (void)ws_size;

    const float* x0 = (const float*)d_in[0];
    const int*   sp[4]; const int* didx[4]; const float* dwp[4];
    const float* Wp[4]; const float* bp[4];
    for (int i = 0; i < 4; ++i) {
        sp[i]   = (const int*)  d_in[1 + i*5 + 0];
        didx[i] = (const int*)  d_in[1 + i*5 + 1];
        dwp[i]  = (const float*)d_in[1 + i*5 + 2];
        Wp[i]   = (const float*)d_in[1 + i*5 + 3];
        bp[i]   = (const float*)d_in[1 + i*5 + 4];
    }
    const float* Wl1 = (const float*)d_in[21];
    const float* bl1 = (const float*)d_in[22];
    const float* Wl2 = (const float*)d_in[23];
    const float* bl2 = (const float*)d_in[24];
    float* out = (float*)d_out;

    char* wsb = (char*)d_ws;
    float* persist      = (float*)wsb;                    // 4 MB   (32,128,256) fp32
    float* partial      = (float*)(wsb + (4<<20));        // 16.8 MB (1024 x 4096 f32)
    _Float16* xT        = (_Float16*)(wsb + (24<<20));    // 8 MB   (2 halves x 4 MB)
    _Float16* pooled0   = (_Float16*)(wsb + (32<<20));    // 16 MB  (32,8192,32) fp16
    _Float16* pooled1   = (_Float16*)(wsb + (48<<20));    // 8 MB   (32,2048,64) fp16
    _Float16* pooled2   = (_Float16*)(wsb + (56<<20));    // 4 MB   (32,512,128) fp16
    unsigned int* gidx0 = (unsigned int*)(wsb + (60<<20));// 0.75 MB
    _Float16* w0h       = (_Float16*)(wsb + (61<<20));
    _Float16* w1h       = w0h + 2048;
    _Float16* w2h       = w1h + 24576;
    _Float16* w3h       = w2h + 98304;

    prep_w0<<<8, 256, 0, stream>>>(Wp[0], w0h);
    prep_w< 384,  64,  64><<<( 24576 + 255)/256, 256, 0, stream>>>(Wp[1], w1h);
    prep_w< 768, 128, 128><<<( 98304 + 255)/256, 256, 0, stream>>>(Wp[2], w2h);
    prep_w<1536, 256,  64><<<(393216 + 255)/256, 256, 0, stream>>>(Wp[3], w3h);
    prep_gidx<<<768, 256, 0, stream>>>(didx[0], sp[0], gidx0);

    // L0: x transpose + batched-M conv0 (2 dispatches of 16 batches each)
    for (int h = 0; h < 2; ++h) {
        _Float16* xTh = xT + (size_t)h*2097152;
        prep_xT<<<512, 256, 0, stream>>>(x0 + (size_t)h*16*98304, xTh);
        conv0T<<<1024, 256, 0, stream>>>(xTh, gidx0, w0h, bp[0], dwp[0],
                                         pooled0 + (size_t)h*16*262144);
    }

    // L1: conv(32->64, K=384) + pool -> fp16 (32, 2048, 64)   [LDS-staged]
    conv_pool_mfma<32,64,64,64,4,1,true><<<1024, 256, 0, stream>>>(
        pooled0, sp[1], w1h, bp[1], didx[1], dwp[1], pooled1, 13, 11, 2);

    // L2: conv(64->128, K=768) + pool -> fp16 (32, 512, 128)  [LDS-staged]
    conv_pool_mfma<64,128,32,128,2,2,true><<<512, 256, 0, stream>>>(
        pooled1, sp[2], w2h, bp[2], didx[2], dwp[2], pooled2, 11, 9, 2);

    // L3: conv(128->256, K=1536) + pool -> fp32 persist (32, 128, 256) [LDS-staged]
    conv_pool_mfma<128,256,32,64,2,2,false><<<dim3(128, 4), 256, 0, stream>>>(
        pooled2, sp[3], w3h, bp[3], didx[3], dwp[3], persist, 9, 7, 2);

    // FC1: (32,32768)@(32768,512), split-K partials then reduce+bias+ELU
    fc1_partial<<<dim3(4, 256), 256, 0, stream>>>(persist, Wl1, partial);
    fc1_reduce<<<64, 256, 0, stream>>>(partial, bl1, out);

    // FC2: (32,512)@(512,64) + bias -> d_out[16384:18432]
    fc2_kernel<<<32, 64, 0, stream>>>(out, Wl2, bl2, out + 16384);
}